// Round 7
// baseline (26582.782 us; speedup 1.0000x reference)
//
#include <hip/hip_runtime.h>

#define Bx 128
#define Sx 512
#define Fx 64
#define Hx 512
#define Xx 128   // 2F

// ---- workspace float offsets ----
#define PARTB_OFF 0ull                             // bwd Wout-partial [B][S][F]
#define H_OFF     ((size_t)Bx * Sx * Fx)           // 4,194,304
#define XH_OFF    (H_OFF + (size_t)2 * 2 * Bx * Hx)
#define BAR_OFF   (XH_OFF + (size_t)2 * Bx * Fx)   // 576 ints: slow ctrs @ g*64
#define FLAG_OFF  (BAR_OFF + 576)

// ---- LDS word offsets ----
#define LDSW_WHH   0
#define LDSW_XIN   26112                       // 3*16*8*68
#define LDSW_WRO   (LDSW_XIN + 32 * 160)
#define LDSW_WOUT  (LDSW_WRO + 2 * 544)
#define LDSW_TOTAL (LDSW_WOUT + 2 * 544 + 16)  // 33424 floats -> 1 wg/CU

struct BParams {
  const float* x; const void* mask;
  const float* Wih_f; const float* Whh_f; const float* bih_f; const float* bhh_f;
  const float* Wro_f; const float* bro_f;
  const float* Wih_b; const float* Whh_b; const float* bih_b; const float* bhh_b;
  const float* Wro_b; const float* bro_b;
  const float* Wout; const float* bout;
  float* out; float* ws;
};

__global__ void detect_kernel(const unsigned int* mask, float* ws) {
  int* bars = (int*)(ws + BAR_OFF);
  int* flag = (int*)(ws + FLAG_OFF);
  int t = threadIdx.x;
  for (int i = t; i < 576; i += blockDim.x) bars[i] = 0;
  if (t == 0) *flag = 0;
  __syncthreads();
  unsigned int v = 0;
  for (int i = t; i < 4096; i += blockDim.x) v |= mask[i] & 0xFFFFFF00u;
  if (v) atomicOr(flag, 1);
}

__global__ void combine_kernel(float* out, const float* partb, const float* bout) {
  int i = blockIdx.x * blockDim.x + threadIdx.x;
  out[i] = out[i] + partb[i] + bout[i & 63];
}

__device__ __forceinline__ void fma4(float& a, float4 w, float4 h) {
  a = fmaf(w.x, h.x, a); a = fmaf(w.y, h.y, a);
  a = fmaf(w.z, h.z, a); a = fmaf(w.w, h.w, a);
}

__device__ __forceinline__ float sel8(const float* a, int idx) {
  float v = a[0];
#pragma unroll
  for (int i = 1; i < 8; ++i) v = (idx == i) ? a[i] : v;
  return v;
}

// System-scope relaxed store: write-through past this XCD's L2 (sc0 sc1) so
// the line is NEVER dirty in L2 -> the barrier's release wbl2 finds nothing
// to flush. Visibility to other XCDs comes from the data being at the
// coherence point by the time the vmcnt(0) in __syncthreads has acked it.
__device__ __forceinline__ void st_sys(float* p, float v) {
  __hip_atomic_store(p, v, __ATOMIC_RELAXED, __HIP_MEMORY_SCOPE_SYSTEM);
}

// 32-member group barrier — the ONLY protocol that has ever passed (rounds
// 2 and 5). Entry __syncthreads drains each wave's stores (vmcnt(0)); the
// agent-scope RELEASE fetch_add publishes; poll; thread0's __threadfence
// (acquire) invalidates stale L1/L2 so plain cached reads refill fresh.
__device__ __forceinline__ void gbar(int* sctr, int nbar) {
  __syncthreads();
  if (threadIdx.x == 0) {
    __hip_atomic_fetch_add(sctr, 1, __ATOMIC_RELEASE, __HIP_MEMORY_SCOPE_AGENT);
    while (__hip_atomic_load(sctr, __ATOMIC_RELAXED, __HIP_MEMORY_SCOPE_AGENT)
           < nbar * 32)
      __builtin_amdgcn_s_sleep(2);
    __threadfence();
  }
  __syncthreads();
}

__global__ void __launch_bounds__(512, 2)
birnn_main(BParams p) {
  extern __shared__ float lds[];

  const int w   = blockIdx.x;
  const int g   = w & 7;         // group = (dir, batch-group)
  const int dir = g >> 2;
  const int bg  = g & 3;
  const int hs  = w >> 3;        // hidden slice 0..31
  const int b0  = bg * 32;
  const int u0  = hs * 16;
  const int f0  = hs * 2;
  const int tid = threadIdx.x;

  const float* Wih = dir ? p.Wih_b : p.Wih_f;
  const float* Whh = dir ? p.Whh_b : p.Whh_f;
  const float* bih = dir ? p.bih_b : p.bih_f;
  const float* bhh = dir ? p.bhh_b : p.bhh_f;
  const float* Wro = dir ? p.Wro_b : p.Wro_f;
  const float* bro = dir ? p.bro_b : p.bro_f;

  float* hbuf = p.ws + H_OFF;
  float* xhb  = p.ws + XH_OFF;
  int*   sctr = (int*)(p.ws + BAR_OFF) + g * 64;
  const int u8f = *(const int*)(p.ws + FLAG_OFF);
  const unsigned char* m8  = (const unsigned char*)p.mask;
  const int*           m32 = (const int*)p.mask;

  float* pout   = dir ? (p.ws + PARTB_OFF) : p.out;  // Wout half-partials
  float* out_xh = p.out + (size_t)(1 + dir) * Bx * Sx * Fx;

  // ---- preload LDS-resident weight slices ----
  for (int idx = tid; idx < 3 * 16 * 512; idx += 512) {
    int g3 = idx >> 13; int rem = idx & 8191;
    int u = rem >> 9;   int j = rem & 511;
    lds[LDSW_WHH + ((g3 * 16 + u) * 8 + (j >> 6)) * 68 + (j & 63)] =
        Whh[(size_t)(g3 * 512 + u0 + u) * Hx + j];
  }
  for (int idx = tid; idx < 2 * 512; idx += 512) {
    int f = idx >> 9, j = idx & 511;
    lds[LDSW_WRO  + f * 544 + (j >> 6) * 68 + (j & 63)] = Wro[(size_t)(f0 + f) * Hx + j];
    lds[LDSW_WOUT + f * 544 + (j >> 6) * 68 + (j & 63)] =
        p.Wout[(size_t)(f0 + f) * (2 * Hx) + dir * Hx + j];
  }

  // ---- init: h=0, xhat=bro, boundary outputs (all system-scope stores) ----
  if (hs == 0) {
    for (int idx = tid; idx < 32 * 512; idx += 512) {
      int b = b0 + (idx >> 9), j = idx & 511;
      st_sys(&hbuf[((size_t)(dir * 2 + 0) * Bx + b) * Hx + j], 0.f);
    }
  }
  if (tid < 64) {
    int b = b0 + (tid >> 1), f = f0 + (tid & 1);
    float br = bro[f];
    st_sys(&xhb[((size_t)dir * Bx + b) * Fx + f], br);
    int T0 = dir ? (Sx - 1) : 0;
    st_sys(&out_xh[((size_t)b * Sx + T0) * Fx + f], br);
    st_sys(&pout  [((size_t)b * Sx + T0) * Fx + f], 0.f);
  }

  // phase-A map: lane = jq(3b) x ulo(3b); wave = bsub(2b) x uhi(1b)
  const int jq   = tid & 7;
  const int ulo  = (tid >> 3) & 7;
  const int wv   = tid >> 6;
  const int bsub = wv & 3;
  const int uhi  = wv >> 2;
  const int u    = uhi * 8 + ulo;
  const int bA   = b0 + bsub * 8;
  const int ru   = u0 + u;
  const int j0   = jq * 64;
  // phase-B map: lane = jq(3b) x blo(3b); wave = bhi(2b) x fB(1b)
  const int blo  = (tid >> 3) & 7;
  const int bB   = b0 + (wv & 3) * 8 + blo;
  const int fB   = wv >> 2;

  // per-thread-invariant Wih rows + gate biases in registers
  float4 wih0[4], wih1[4], wih2[4];
#pragma unroll
  for (int q = 0; q < 4; ++q) {
    wih0[q] = *(const float4*)(Wih + (size_t)(0 * 512 + ru) * Xx + jq * 16 + q * 4);
    wih1[q] = *(const float4*)(Wih + (size_t)(1 * 512 + ru) * Xx + jq * 16 + q * 4);
    wih2[q] = *(const float4*)(Wih + (size_t)(2 * 512 + ru) * Xx + jq * 16 + q * 4);
  }
  const float bs_r = bih[ru] + bhh[ru];
  const float bs_z = bih[512 + ru] + bhh[512 + ru];
  const float bs_i = bih[1024 + ru];
  const float bs_h = bhh[1024 + ru];

  const float* w0p = lds + LDSW_WHH + ((0 * 16 + u) * 8 + jq) * 68;
  const float* w1p = lds + LDSW_WHH + ((1 * 16 + u) * 8 + jq) * 68;
  const float* w2p = lds + LDSW_WHH + ((2 * 16 + u) * 8 + jq) * 68;

  float hprev_own = 0.f;   // h[bA+jq][ru], written by this thread every step

  int nbar = 1;
  gbar(sctr, nbar);   // publish init

  for (int k = 1; k < Sx; ++k) {
    const int pp = k & 1, pr = pp ^ 1;
    const int t_in = dir ? (Sx - k) : (k - 1);

    // ---- stage x_in = [x_p, m] into LDS (vectorized, plain loads) ----
    {
      int bl = tid >> 4, sub = tid & 15;
      int b = b0 + bl;
      float* xr = lds + LDSW_XIN + bl * 160 + (sub >> 1) * 20 + (sub & 1) * 8;
      float v[8];
      if (sub < 8) {
        size_t base = ((size_t)b * Sx + t_in) * Fx + sub * 8;
        float4 xa = *(const float4*)(p.x + base);
        float4 xb = *(const float4*)(p.x + base + 4);
        const float* xhp = xhb + ((size_t)dir * Bx + b) * Fx + sub * 8;
        float4 ha  = *(const float4*)(xhp);
        float4 hb4 = *(const float4*)(xhp + 4);
        int mi[8];
        if (u8f) {
          unsigned long long mm = *(const unsigned long long*)(m8 + base);
#pragma unroll
          for (int j = 0; j < 8; ++j) mi[j] = (int)((mm >> (8 * j)) & 0xFF);
        } else {
          int4 ma = *(const int4*)(m32 + base);
          int4 mb = *(const int4*)(m32 + base + 4);
          mi[0] = ma.x; mi[1] = ma.y; mi[2] = ma.z; mi[3] = ma.w;
          mi[4] = mb.x; mi[5] = mb.y; mi[6] = mb.z; mi[7] = mb.w;
        }
        v[0] = mi[0] ? xa.x : ha.x;  v[1] = mi[1] ? xa.y : ha.y;
        v[2] = mi[2] ? xa.z : ha.z;  v[3] = mi[3] ? xa.w : ha.w;
        v[4] = mi[4] ? xb.x : hb4.x; v[5] = mi[5] ? xb.y : hb4.y;
        v[6] = mi[6] ? xb.z : hb4.z; v[7] = mi[7] ? xb.w : hb4.w;
      } else {
        size_t base = ((size_t)b * Sx + t_in) * Fx + (sub - 8) * 8;
        if (u8f) {
          unsigned long long mm = *(const unsigned long long*)(m8 + base);
#pragma unroll
          for (int j = 0; j < 8; ++j) v[j] = (float)((mm >> (8 * j)) & 0xFF);
        } else {
          int4 ma = *(const int4*)(m32 + base);
          int4 mb = *(const int4*)(m32 + base + 4);
          v[0] = (float)ma.x; v[1] = (float)ma.y; v[2] = (float)ma.z; v[3] = (float)ma.w;
          v[4] = (float)mb.x; v[5] = (float)mb.y; v[6] = (float)mb.z; v[7] = (float)mb.w;
        }
      }
      *(float4*)(xr)     = make_float4(v[0], v[1], v[2], v[3]);
      *(float4*)(xr + 4) = make_float4(v[4], v[5], v[6], v[7]);
    }
    __syncthreads();

    float acc0[8], acc1[8], acc2[8], acc3[8];
#pragma unroll
    for (int i = 0; i < 8; ++i) { acc0[i] = 0.f; acc1[i] = 0.f; acc2[i] = 0.f; acc3[i] = 0.f; }

    // ---- gh: Whh slice (LDS) x h_prev (plain cached loads, fresh via acquire) ----
    {
      const float* hrd = hbuf + (size_t)(dir * 2 + pr) * Bx * Hx;
#pragma unroll 2
      for (int jj = 0; jj < 64; jj += 4) {
        float4 w0 = *(const float4*)(w0p + jj);
        float4 w1 = *(const float4*)(w1p + jj);
        float4 w2 = *(const float4*)(w2p + jj);
#pragma unroll
        for (int bb = 0; bb < 8; ++bb) {
          float4 h4 = *(const float4*)(hrd + (size_t)(bA + bb) * Hx + j0 + jj);
          fma4(acc0[bb], w0, h4);
          fma4(acc1[bb], w1, h4);
          fma4(acc3[bb], w2, h4);
        }
      }
    }
    // ---- gi: Wih rows (registers) x x_in (LDS) ----
    {
      const float* xinb = lds + LDSW_XIN;
#pragma unroll
      for (int q = 0; q < 4; ++q) {
        float4 w0 = wih0[q], w1 = wih1[q], w2 = wih2[q];
        int off = jq * 20 + q * 4;
#pragma unroll
        for (int bb = 0; bb < 8; ++bb) {
          float4 xv = *(const float4*)(xinb + (bsub * 8 + bb) * 160 + off);
          fma4(acc0[bb], w0, xv);
          fma4(acc1[bb], w1, xv);
          fma4(acc2[bb], w2, xv);
        }
      }
    }
    // ---- reduce across jq ----
#pragma unroll
    for (int m = 1; m <= 4; m <<= 1) {
#pragma unroll
      for (int bb = 0; bb < 8; ++bb) {
        acc0[bb] += __shfl_xor(acc0[bb], m);
        acc1[bb] += __shfl_xor(acc1[bb], m);
        acc2[bb] += __shfl_xor(acc2[bb], m);
        acc3[bb] += __shfl_xor(acc3[bb], m);
      }
    }
    // ---- gates: lane jq handles batch bA+jq; h_prev from register ----
    {
      int b = bA + jq;
      float sr  = sel8(acc0, jq);
      float sz  = sel8(acc1, jq);
      float sgi = sel8(acc2, jq);
      float sgh = sel8(acc3, jq);
      float r = 1.f / (1.f + __expf(-(sr + bs_r)));
      float z = 1.f / (1.f + __expf(-(sz + bs_z)));
      float n = tanhf(sgi + bs_i + r * (sgh + bs_h));
      float hn = (1.f - z) * n + z * hprev_own;
      hprev_own = hn;
      st_sys(&hbuf[(size_t)(dir * 2 + pp) * Bx * Hx + (size_t)b * Hx + ru], hn);
    }
    ++nbar;
    gbar(sctr, nbar);   // h_new visible to group

    // ---- phase B: xhat = Wro@h + bro ; Wout-half partial ----
    {
      const float* hnw  = hbuf + (size_t)(dir * 2 + pp) * Bx * Hx;
      const float* wroL = lds + LDSW_WRO  + fB * 544 + jq * 68;
      const float* wouL = lds + LDSW_WOUT + fB * 544 + jq * 68;
      const float* hb   = hnw + (size_t)bB * Hx + jq * 64;
      float ax = 0.f, ap = 0.f;
#pragma unroll 2
      for (int jj = 0; jj < 64; jj += 4) {
        float4 h4 = *(const float4*)(hb + jj);
        float4 wx = *(const float4*)(wroL + jj);
        float4 wp = *(const float4*)(wouL + jj);
        fma4(ax, wx, h4);
        fma4(ap, wp, h4);
      }
#pragma unroll
      for (int m = 1; m <= 4; m <<= 1) {
        ax += __shfl_xor(ax, m);
        ap += __shfl_xor(ap, m);
      }
      const int T = dir ? (Sx - 1 - k) : k;
      const int f = f0 + fB;
      if (jq == 0) {
        float v = ax + bro[f];
        st_sys(&xhb[((size_t)dir * Bx + bB) * Fx + f], v);
        st_sys(&out_xh[((size_t)bB * Sx + T) * Fx + f], v);
      } else if (jq == 1) {
        st_sys(&pout[((size_t)bB * Sx + T) * Fx + f], ap);   // pure write
      }
    }
    ++nbar;
    gbar(sctr, nbar);   // xhb visible for next staging
  }
}

extern "C" void kernel_launch(void* const* d_in, const int* in_sizes, int n_in,
                              void* d_out, int out_size, void* d_ws, size_t ws_size,
                              hipStream_t stream) {
  (void)in_sizes; (void)n_in; (void)out_size; (void)ws_size;
  float* ws = (float*)d_ws;

  detect_kernel<<<1, 512, 0, stream>>>((const unsigned int*)d_in[1], ws);

  BParams p;
  p.x     = (const float*)d_in[0];  p.mask = d_in[1];
  p.Wih_f = (const float*)d_in[2];  p.Whh_f = (const float*)d_in[3];
  p.bih_f = (const float*)d_in[4];  p.bhh_f = (const float*)d_in[5];
  p.Wro_f = (const float*)d_in[6];  p.bro_f = (const float*)d_in[7];
  p.Wih_b = (const float*)d_in[8];  p.Whh_b = (const float*)d_in[9];
  p.bih_b = (const float*)d_in[10]; p.bhh_b = (const float*)d_in[11];
  p.Wro_b = (const float*)d_in[12]; p.bro_b = (const float*)d_in[13];
  p.Wout  = (const float*)d_in[14]; p.bout  = (const float*)d_in[15];
  p.out   = (float*)d_out;
  p.ws    = ws;

  hipFuncSetAttribute(reinterpret_cast<const void*>(birnn_main),
                      hipFuncAttributeMaxDynamicSharedMemorySize,
                      (int)(LDSW_TOTAL * sizeof(float)));
  void* args[] = { (void*)&p };
  hipLaunchCooperativeKernel(reinterpret_cast<void*>(birnn_main),
                             dim3(256), dim3(512), args,
                             (unsigned)(LDSW_TOTAL * sizeof(float)), stream);

  combine_kernel<<<dim3(Bx * Sx * Fx / 256), dim3(256), 0, stream>>>(
      (float*)d_out, ws + PARTB_OFF, (const float*)d_in[15]);
}

// Round 8
// 24702.040 us; speedup vs baseline: 1.0761x; 1.0761x over previous
//
#include <hip/hip_runtime.h>

#define Bx 128
#define Sx 512
#define Fx 64
#define Hx 512
#define Xx 128   // 2F

// ---- workspace float offsets ----
#define PARTB_OFF 0ull                             // bwd Wout-partial [B][S][F]
#define H_OFF     ((size_t)Bx * Sx * Fx)           // 4,194,304
#define XH_OFF    (H_OFF + (size_t)2 * 2 * Bx * Hx)
#define BAR_OFF   (XH_OFF + (size_t)2 * Bx * Fx)   // 576 ints: ctrs @ g*64
#define FLAG_OFF  (BAR_OFF + 576)

// ---- LDS word offsets ----
#define LDSW_WHH   0
#define LDSW_XIN   26112                       // 3*16*8*68
#define LDSW_WRO   (LDSW_XIN + 32 * 160)
#define LDSW_WOUT  (LDSW_WRO + 2 * 544)
#define LDSW_TOTAL (LDSW_WOUT + 2 * 544 + 16)  // 33424 floats -> 1 wg/CU

struct BParams {
  const float* x; const void* mask;
  const float* Wih_f; const float* Whh_f; const float* bih_f; const float* bhh_f;
  const float* Wro_f; const float* bro_f;
  const float* Wih_b; const float* Whh_b; const float* bih_b; const float* bhh_b;
  const float* Wro_b; const float* bro_b;
  const float* Wout; const float* bout;
  float* out; float* ws;
};

__global__ void detect_kernel(const unsigned int* mask, float* ws) {
  int* bars = (int*)(ws + BAR_OFF);
  int* flag = (int*)(ws + FLAG_OFF);
  int t = threadIdx.x;
  for (int i = t; i < 576; i += blockDim.x) bars[i] = 0;
  if (t == 0) *flag = 0;
  __syncthreads();
  unsigned int v = 0;
  for (int i = t; i < 4096; i += blockDim.x) v |= mask[i] & 0xFFFFFF00u;
  if (v) atomicOr(flag, 1);
}

__global__ void combine_kernel(float* out, const float* partb, const float* bout) {
  int i = blockIdx.x * blockDim.x + threadIdx.x;
  out[i] = out[i] + partb[i] + bout[i & 63];
}

__device__ __forceinline__ void fma4(float& a, float4 w, float4 h) {
  a = fmaf(w.x, h.x, a); a = fmaf(w.y, h.y, a);
  a = fmaf(w.z, h.z, a); a = fmaf(w.w, h.w, a);
}

__device__ __forceinline__ float sel8(const float* a, int idx) {
  float v = a[0];
#pragma unroll
  for (int i = 1; i < 8; ++i) v = (idx == i) ? a[i] : v;
  return v;
}

// System-scope relaxed store: write-through past L2 (sc0 sc1). The line is
// never dirty in L2, and vmcnt-ack means the store reached the coherence
// point -> no release flush is needed at the barrier.
__device__ __forceinline__ void st_sys(float* p, float v) {
  __hip_atomic_store(p, v, __ATOMIC_RELAXED, __HIP_MEMORY_SCOPE_SYSTEM);
}

// 32-member group barrier. All shared data was stored with st_sys and acked
// by the vmcnt(0) inside the entry __syncthreads => already at the coherence
// point. Arrival is therefore a RELAXED fetch_add (bare global_atomic_add,
// NO buffer_wbl2 dirty-walk — that walk was the serialized ~10us/barrier in
// rounds 2/5/7). Thread0's __threadfence acquire remains: consumers hold
// stale L2 lines of the ping-pong h buffer and must invalidate before reads.
__device__ __forceinline__ void gbar(int* sctr, int nbar) {
  __syncthreads();
  if (threadIdx.x == 0) {
    __hip_atomic_fetch_add(sctr, 1, __ATOMIC_RELAXED, __HIP_MEMORY_SCOPE_AGENT);
    while (__hip_atomic_load(sctr, __ATOMIC_RELAXED, __HIP_MEMORY_SCOPE_AGENT)
           < nbar * 32)
      __builtin_amdgcn_s_sleep(2);
    __threadfence();
  }
  __syncthreads();
}

__global__ void __launch_bounds__(512, 2)
birnn_main(BParams p) {
  extern __shared__ float lds[];

  const int w   = blockIdx.x;
  const int g   = w & 7;         // group = (dir, batch-group)
  const int dir = g >> 2;
  const int bg  = g & 3;
  const int hs  = w >> 3;        // hidden slice 0..31
  const int b0  = bg * 32;
  const int u0  = hs * 16;
  const int f0  = hs * 2;
  const int tid = threadIdx.x;

  const float* Wih = dir ? p.Wih_b : p.Wih_f;
  const float* Whh = dir ? p.Whh_b : p.Whh_f;
  const float* bih = dir ? p.bih_b : p.bih_f;
  const float* bhh = dir ? p.bhh_b : p.bhh_f;
  const float* Wro = dir ? p.Wro_b : p.Wro_f;
  const float* bro = dir ? p.bro_b : p.bro_f;

  float* hbuf = p.ws + H_OFF;
  float* xhb  = p.ws + XH_OFF;
  int*   sctr = (int*)(p.ws + BAR_OFF) + g * 64;
  const int u8f = *(const int*)(p.ws + FLAG_OFF);
  const unsigned char* m8  = (const unsigned char*)p.mask;
  const int*           m32 = (const int*)p.mask;

  float* pout   = dir ? (p.ws + PARTB_OFF) : p.out;  // Wout half-partials
  float* out_xh = p.out + (size_t)(1 + dir) * Bx * Sx * Fx;

  // ---- preload LDS-resident weight slices ----
  for (int idx = tid; idx < 3 * 16 * 512; idx += 512) {
    int g3 = idx >> 13; int rem = idx & 8191;
    int u = rem >> 9;   int j = rem & 511;
    lds[LDSW_WHH + ((g3 * 16 + u) * 8 + (j >> 6)) * 68 + (j & 63)] =
        Whh[(size_t)(g3 * 512 + u0 + u) * Hx + j];
  }
  for (int idx = tid; idx < 2 * 512; idx += 512) {
    int f = idx >> 9, j = idx & 511;
    lds[LDSW_WRO  + f * 544 + (j >> 6) * 68 + (j & 63)] = Wro[(size_t)(f0 + f) * Hx + j];
    lds[LDSW_WOUT + f * 544 + (j >> 6) * 68 + (j & 63)] =
        p.Wout[(size_t)(f0 + f) * (2 * Hx) + dir * Hx + j];
  }

  // ---- init: h=0, xhat=bro, boundary outputs (all system-scope stores) ----
  if (hs == 0) {
    for (int idx = tid; idx < 32 * 512; idx += 512) {
      int b = b0 + (idx >> 9), j = idx & 511;
      st_sys(&hbuf[((size_t)(dir * 2 + 0) * Bx + b) * Hx + j], 0.f);
    }
  }
  if (tid < 64) {
    int b = b0 + (tid >> 1), f = f0 + (tid & 1);
    float br = bro[f];
    st_sys(&xhb[((size_t)dir * Bx + b) * Fx + f], br);
    int T0 = dir ? (Sx - 1) : 0;
    st_sys(&out_xh[((size_t)b * Sx + T0) * Fx + f], br);
    st_sys(&pout  [((size_t)b * Sx + T0) * Fx + f], 0.f);
  }

  // phase-A map: lane = jq(3b) x ulo(3b); wave = bsub(2b) x uhi(1b)
  const int jq   = tid & 7;
  const int ulo  = (tid >> 3) & 7;
  const int wv   = tid >> 6;
  const int bsub = wv & 3;
  const int uhi  = wv >> 2;
  const int u    = uhi * 8 + ulo;
  const int bA   = b0 + bsub * 8;
  const int ru   = u0 + u;
  const int j0   = jq * 64;
  // phase-B map: lane = jq(3b) x blo(3b); wave = bhi(2b) x fB(1b)
  const int blo  = (tid >> 3) & 7;
  const int bB   = b0 + (wv & 3) * 8 + blo;
  const int fB   = wv >> 2;

  // per-thread-invariant Wih rows + gate biases in registers
  float4 wih0[4], wih1[4], wih2[4];
#pragma unroll
  for (int q = 0; q < 4; ++q) {
    wih0[q] = *(const float4*)(Wih + (size_t)(0 * 512 + ru) * Xx + jq * 16 + q * 4);
    wih1[q] = *(const float4*)(Wih + (size_t)(1 * 512 + ru) * Xx + jq * 16 + q * 4);
    wih2[q] = *(const float4*)(Wih + (size_t)(2 * 512 + ru) * Xx + jq * 16 + q * 4);
  }
  const float bs_r = bih[ru] + bhh[ru];
  const float bs_z = bih[512 + ru] + bhh[512 + ru];
  const float bs_i = bih[1024 + ru];
  const float bs_h = bhh[1024 + ru];

  const float* w0p = lds + LDSW_WHH + ((0 * 16 + u) * 8 + jq) * 68;
  const float* w1p = lds + LDSW_WHH + ((1 * 16 + u) * 8 + jq) * 68;
  const float* w2p = lds + LDSW_WHH + ((2 * 16 + u) * 8 + jq) * 68;

  float hprev_own = 0.f;   // h[bA+jq][ru], written by this thread every step

  int nbar = 1;
  gbar(sctr, nbar);   // publish init

  for (int k = 1; k < Sx; ++k) {
    const int pp = k & 1, pr = pp ^ 1;
    const int t_in = dir ? (Sx - k) : (k - 1);

    // ---- stage x_in = [x_p, m] into LDS (vectorized, plain loads) ----
    {
      int bl = tid >> 4, sub = tid & 15;
      int b = b0 + bl;
      float* xr = lds + LDSW_XIN + bl * 160 + (sub >> 1) * 20 + (sub & 1) * 8;
      float v[8];
      if (sub < 8) {
        size_t base = ((size_t)b * Sx + t_in) * Fx + sub * 8;
        float4 xa = *(const float4*)(p.x + base);
        float4 xb = *(const float4*)(p.x + base + 4);
        const float* xhp = xhb + ((size_t)dir * Bx + b) * Fx + sub * 8;
        float4 ha  = *(const float4*)(xhp);
        float4 hb4 = *(const float4*)(xhp + 4);
        int mi[8];
        if (u8f) {
          unsigned long long mm = *(const unsigned long long*)(m8 + base);
#pragma unroll
          for (int j = 0; j < 8; ++j) mi[j] = (int)((mm >> (8 * j)) & 0xFF);
        } else {
          int4 ma = *(const int4*)(m32 + base);
          int4 mb = *(const int4*)(m32 + base + 4);
          mi[0] = ma.x; mi[1] = ma.y; mi[2] = ma.z; mi[3] = ma.w;
          mi[4] = mb.x; mi[5] = mb.y; mi[6] = mb.z; mi[7] = mb.w;
        }
        v[0] = mi[0] ? xa.x : ha.x;  v[1] = mi[1] ? xa.y : ha.y;
        v[2] = mi[2] ? xa.z : ha.z;  v[3] = mi[3] ? xa.w : ha.w;
        v[4] = mi[4] ? xb.x : hb4.x; v[5] = mi[5] ? xb.y : hb4.y;
        v[6] = mi[6] ? xb.z : hb4.z; v[7] = mi[7] ? xb.w : hb4.w;
      } else {
        size_t base = ((size_t)b * Sx + t_in) * Fx + (sub - 8) * 8;
        if (u8f) {
          unsigned long long mm = *(const unsigned long long*)(m8 + base);
#pragma unroll
          for (int j = 0; j < 8; ++j) v[j] = (float)((mm >> (8 * j)) & 0xFF);
        } else {
          int4 ma = *(const int4*)(m32 + base);
          int4 mb = *(const int4*)(m32 + base + 4);
          v[0] = (float)ma.x; v[1] = (float)ma.y; v[2] = (float)ma.z; v[3] = (float)ma.w;
          v[4] = (float)mb.x; v[5] = (float)mb.y; v[6] = (float)mb.z; v[7] = (float)mb.w;
        }
      }
      *(float4*)(xr)     = make_float4(v[0], v[1], v[2], v[3]);
      *(float4*)(xr + 4) = make_float4(v[4], v[5], v[6], v[7]);
    }
    __syncthreads();

    float acc0[8], acc1[8], acc2[8], acc3[8];
#pragma unroll
    for (int i = 0; i < 8; ++i) { acc0[i] = 0.f; acc1[i] = 0.f; acc2[i] = 0.f; acc3[i] = 0.f; }

    // ---- gh: Whh slice (LDS) x h_prev (plain cached loads, fresh via acquire) ----
    {
      const float* hrd = hbuf + (size_t)(dir * 2 + pr) * Bx * Hx;
#pragma unroll 2
      for (int jj = 0; jj < 64; jj += 4) {
        float4 w0 = *(const float4*)(w0p + jj);
        float4 w1 = *(const float4*)(w1p + jj);
        float4 w2 = *(const float4*)(w2p + jj);
#pragma unroll
        for (int bb = 0; bb < 8; ++bb) {
          float4 h4 = *(const float4*)(hrd + (size_t)(bA + bb) * Hx + j0 + jj);
          fma4(acc0[bb], w0, h4);
          fma4(acc1[bb], w1, h4);
          fma4(acc3[bb], w2, h4);
        }
      }
    }
    // ---- gi: Wih rows (registers) x x_in (LDS) ----
    {
      const float* xinb = lds + LDSW_XIN;
#pragma unroll
      for (int q = 0; q < 4; ++q) {
        float4 w0 = wih0[q], w1 = wih1[q], w2 = wih2[q];
        int off = jq * 20 + q * 4;
#pragma unroll
        for (int bb = 0; bb < 8; ++bb) {
          float4 xv = *(const float4*)(xinb + (bsub * 8 + bb) * 160 + off);
          fma4(acc0[bb], w0, xv);
          fma4(acc1[bb], w1, xv);
          fma4(acc2[bb], w2, xv);
        }
      }
    }
    // ---- reduce across jq ----
#pragma unroll
    for (int m = 1; m <= 4; m <<= 1) {
#pragma unroll
      for (int bb = 0; bb < 8; ++bb) {
        acc0[bb] += __shfl_xor(acc0[bb], m);
        acc1[bb] += __shfl_xor(acc1[bb], m);
        acc2[bb] += __shfl_xor(acc2[bb], m);
        acc3[bb] += __shfl_xor(acc3[bb], m);
      }
    }
    // ---- gates: lane jq handles batch bA+jq; h_prev from register ----
    {
      int b = bA + jq;
      float sr  = sel8(acc0, jq);
      float sz  = sel8(acc1, jq);
      float sgi = sel8(acc2, jq);
      float sgh = sel8(acc3, jq);
      float r = 1.f / (1.f + __expf(-(sr + bs_r)));
      float z = 1.f / (1.f + __expf(-(sz + bs_z)));
      float n = tanhf(sgi + bs_i + r * (sgh + bs_h));
      float hn = (1.f - z) * n + z * hprev_own;
      hprev_own = hn;
      st_sys(&hbuf[(size_t)(dir * 2 + pp) * Bx * Hx + (size_t)b * Hx + ru], hn);
    }
    ++nbar;
    gbar(sctr, nbar);   // h_new visible to group

    // ---- phase B: xhat = Wro@h + bro ; Wout-half partial ----
    {
      const float* hnw  = hbuf + (size_t)(dir * 2 + pp) * Bx * Hx;
      const float* wroL = lds + LDSW_WRO  + fB * 544 + jq * 68;
      const float* wouL = lds + LDSW_WOUT + fB * 544 + jq * 68;
      const float* hb   = hnw + (size_t)bB * Hx + jq * 64;
      float ax = 0.f, ap = 0.f;
#pragma unroll 2
      for (int jj = 0; jj < 64; jj += 4) {
        float4 h4 = *(const float4*)(hb + jj);
        float4 wx = *(const float4*)(wroL + jj);
        float4 wp = *(const float4*)(wouL + jj);
        fma4(ax, wx, h4);
        fma4(ap, wp, h4);
      }
#pragma unroll
      for (int m = 1; m <= 4; m <<= 1) {
        ax += __shfl_xor(ax, m);
        ap += __shfl_xor(ap, m);
      }
      const int T = dir ? (Sx - 1 - k) : k;
      const int f = f0 + fB;
      if (jq == 0) {
        float v = ax + bro[f];
        st_sys(&xhb[((size_t)dir * Bx + bB) * Fx + f], v);
        st_sys(&out_xh[((size_t)bB * Sx + T) * Fx + f], v);
      } else if (jq == 1) {
        st_sys(&pout[((size_t)bB * Sx + T) * Fx + f], ap);   // pure write
      }
    }
    ++nbar;
    gbar(sctr, nbar);   // xhb visible for next staging
  }
}

extern "C" void kernel_launch(void* const* d_in, const int* in_sizes, int n_in,
                              void* d_out, int out_size, void* d_ws, size_t ws_size,
                              hipStream_t stream) {
  (void)in_sizes; (void)n_in; (void)out_size; (void)ws_size;
  float* ws = (float*)d_ws;

  detect_kernel<<<1, 512, 0, stream>>>((const unsigned int*)d_in[1], ws);

  BParams p;
  p.x     = (const float*)d_in[0];  p.mask = d_in[1];
  p.Wih_f = (const float*)d_in[2];  p.Whh_f = (const float*)d_in[3];
  p.bih_f = (const float*)d_in[4];  p.bhh_f = (const float*)d_in[5];
  p.Wro_f = (const float*)d_in[6];  p.bro_f = (const float*)d_in[7];
  p.Wih_b = (const float*)d_in[8];  p.Whh_b = (const float*)d_in[9];
  p.bih_b = (const float*)d_in[10]; p.bhh_b = (const float*)d_in[11];
  p.Wro_b = (const float*)d_in[12]; p.bro_b = (const float*)d_in[13];
  p.Wout  = (const float*)d_in[14]; p.bout  = (const float*)d_in[15];
  p.out   = (float*)d_out;
  p.ws    = ws;

  hipFuncSetAttribute(reinterpret_cast<const void*>(birnn_main),
                      hipFuncAttributeMaxDynamicSharedMemorySize,
                      (int)(LDSW_TOTAL * sizeof(float)));
  void* args[] = { (void*)&p };
  hipLaunchCooperativeKernel(reinterpret_cast<void*>(birnn_main),
                             dim3(256), dim3(512), args,
                             (unsigned)(LDSW_TOTAL * sizeof(float)), stream);

  combine_kernel<<<dim3(Bx * Sx * Fx / 256), dim3(256), 0, stream>>>(
      (float*)d_out, ws + PARTB_OFF, (const float*)d_in[15]);
}

// Round 9
// 24522.005 us; speedup vs baseline: 1.0840x; 1.0073x over previous
//
#include <hip/hip_runtime.h>

#define Bx 128
#define Sx 512
#define Fx 64
#define Hx 512
#define Xx 128   // 2F

// ---- workspace float offsets ----
#define PARTB_OFF 0ull                             // bwd Wout-partial [B][S][F]
#define H_OFF     ((size_t)Bx * Sx * Fx)           // 4,194,304
#define XH_OFF    (H_OFF + (size_t)2 * 2 * Bx * Hx)
#define BAR_OFF   (XH_OFF + (size_t)2 * Bx * Fx)   // 4096 ints: 8 grp x 32 slot x 16
#define FLAG_OFF  (BAR_OFF + 4096)

// ---- LDS word offsets ----
#define LDSW_WHH   0
#define LDSW_XIN   26112                       // 3*16*8*68
#define LDSW_WRO   (LDSW_XIN + 32 * 160)
#define LDSW_WOUT  (LDSW_WRO + 2 * 544)
#define LDSW_TOTAL (LDSW_WOUT + 2 * 544 + 16)  // 33424 floats -> 1 wg/CU

struct BParams {
  const float* x; const void* mask;
  const float* Wih_f; const float* Whh_f; const float* bih_f; const float* bhh_f;
  const float* Wro_f; const float* bro_f;
  const float* Wih_b; const float* Whh_b; const float* bih_b; const float* bhh_b;
  const float* Wro_b; const float* bro_b;
  const float* Wout; const float* bout;
  float* out; float* ws;
};

__global__ void detect_kernel(const unsigned int* mask, float* ws) {
  int* bars = (int*)(ws + BAR_OFF);
  int* flag = (int*)(ws + FLAG_OFF);
  int t = threadIdx.x;
  for (int i = t; i < 4096; i += blockDim.x) bars[i] = 0;
  if (t == 0) *flag = 0;
  __syncthreads();
  unsigned int v = 0;
  for (int i = t; i < 4096; i += blockDim.x) v |= mask[i] & 0xFFFFFF00u;
  if (v) atomicOr(flag, 1);
}

__global__ void combine_kernel(float* out, const float* partb, const float* bout) {
  int i = blockIdx.x * blockDim.x + threadIdx.x;
  out[i] = out[i] + partb[i] + bout[i & 63];
}

__device__ __forceinline__ void fma4(float& a, float4 w, float4 h) {
  a = fmaf(w.x, h.x, a); a = fmaf(w.y, h.y, a);
  a = fmaf(w.z, h.z, a); a = fmaf(w.w, h.w, a);
}

__device__ __forceinline__ float sel8(const float* a, int idx) {
  float v = a[0];
#pragma unroll
  for (int i = 1; i < 8; ++i) v = (idx == i) ? a[i] : v;
  return v;
}

// System-scope relaxed store: write-through past L2 (never dirty; at the
// coherence point once vmcnt-acked). Proven by rounds 7/8.
__device__ __forceinline__ void st_sys(float* p, float v) {
  __hip_atomic_store(p, v, __ATOMIC_RELAXED, __HIP_MEMORY_SCOPE_SYSTEM);
}
__device__ __forceinline__ void st_sys_i(int* p, int v) {
  __hip_atomic_store(p, v, __ATOMIC_RELAXED, __HIP_MEMORY_SCOPE_SYSTEM);
}

// 32-member group barrier, ordinal nbar (monotonic).
// Round-8 proved the visibility chain {st_sys data, syncthreads(vmcnt0),
// RELAXED signal, agent-relaxed poll, threadfence acquire} is sufficient.
// This round replaces the signal: instead of 32 serialized RMWs on one
// line (~10us: ownership migration across 8 XCDs), each wg STOREs its
// ordinal to its own 64B-spaced slot (write-through; arrivals pipeline in
// parallel). Wave 0 polls all 32 slots in parallel with the same
// agent-relaxed atomic load used (and proven visible) in every passing
// round, then executes the acquire threadfence.
__device__ __forceinline__ void gbar(int* slots, int hs, int nbar) {
  __syncthreads();   // vmcnt(0): all waves' st_sys data at coherence point
  if (threadIdx.x < 64) {
    if (threadIdx.x == 0) st_sys_i(slots + hs * 16, nbar);
    const int* myslot = slots + (threadIdx.x & 31) * 16;
    for (;;) {
      int v = __hip_atomic_load(myslot, __ATOMIC_RELAXED, __HIP_MEMORY_SCOPE_AGENT);
      if (__all(v >= nbar)) break;
      __builtin_amdgcn_s_sleep(1);
    }
    __threadfence();   // acquire: invalidate stale L1/L2 before reads
  }
  __syncthreads();
}

__global__ void __launch_bounds__(512, 2)
birnn_main(BParams p) {
  extern __shared__ float lds[];

  const int w   = blockIdx.x;
  const int g   = w & 7;         // group = (dir, batch-group)
  const int dir = g >> 2;
  const int bg  = g & 3;
  const int hs  = w >> 3;        // hidden slice 0..31 (= slot index)
  const int b0  = bg * 32;
  const int u0  = hs * 16;
  const int f0  = hs * 2;
  const int tid = threadIdx.x;

  const float* Wih = dir ? p.Wih_b : p.Wih_f;
  const float* Whh = dir ? p.Whh_b : p.Whh_f;
  const float* bih = dir ? p.bih_b : p.bih_f;
  const float* bhh = dir ? p.bhh_b : p.bhh_f;
  const float* Wro = dir ? p.Wro_b : p.Wro_f;
  const float* bro = dir ? p.bro_b : p.bro_f;

  float* hbuf  = p.ws + H_OFF;
  float* xhb   = p.ws + XH_OFF;
  int*   slots = (int*)(p.ws + BAR_OFF) + g * 512;
  const int u8f = *(const int*)(p.ws + FLAG_OFF);
  const unsigned char* m8  = (const unsigned char*)p.mask;
  const int*           m32 = (const int*)p.mask;

  float* pout   = dir ? (p.ws + PARTB_OFF) : p.out;  // Wout half-partials
  float* out_xh = p.out + (size_t)(1 + dir) * Bx * Sx * Fx;

  // ---- preload LDS-resident weight slices ----
  for (int idx = tid; idx < 3 * 16 * 512; idx += 512) {
    int g3 = idx >> 13; int rem = idx & 8191;
    int u = rem >> 9;   int j = rem & 511;
    lds[LDSW_WHH + ((g3 * 16 + u) * 8 + (j >> 6)) * 68 + (j & 63)] =
        Whh[(size_t)(g3 * 512 + u0 + u) * Hx + j];
  }
  for (int idx = tid; idx < 2 * 512; idx += 512) {
    int f = idx >> 9, j = idx & 511;
    lds[LDSW_WRO  + f * 544 + (j >> 6) * 68 + (j & 63)] = Wro[(size_t)(f0 + f) * Hx + j];
    lds[LDSW_WOUT + f * 544 + (j >> 6) * 68 + (j & 63)] =
        p.Wout[(size_t)(f0 + f) * (2 * Hx) + dir * Hx + j];
  }

  // ---- init: h=0, xhat=bro, boundary outputs (all system-scope stores) ----
  if (hs == 0) {
    for (int idx = tid; idx < 32 * 512; idx += 512) {
      int b = b0 + (idx >> 9), j = idx & 511;
      st_sys(&hbuf[((size_t)(dir * 2 + 0) * Bx + b) * Hx + j], 0.f);
    }
  }
  if (tid < 64) {
    int b = b0 + (tid >> 1), f = f0 + (tid & 1);
    float br = bro[f];
    st_sys(&xhb[((size_t)dir * Bx + b) * Fx + f], br);
    int T0 = dir ? (Sx - 1) : 0;
    st_sys(&out_xh[((size_t)b * Sx + T0) * Fx + f], br);
    st_sys(&pout  [((size_t)b * Sx + T0) * Fx + f], 0.f);
  }

  // phase-A map: lane = jq(3b) x ulo(3b); wave = bsub(2b) x uhi(1b)
  const int jq   = tid & 7;
  const int ulo  = (tid >> 3) & 7;
  const int wv   = tid >> 6;
  const int bsub = wv & 3;
  const int uhi  = wv >> 2;
  const int u    = uhi * 8 + ulo;
  const int bA   = b0 + bsub * 8;
  const int ru   = u0 + u;
  const int j0   = jq * 64;
  // phase-B map: lane = jq(3b) x blo(3b); wave = bhi(2b) x fB(1b)
  const int blo  = (tid >> 3) & 7;
  const int bB   = b0 + (wv & 3) * 8 + blo;
  const int fB   = wv >> 2;

  // per-thread-invariant Wih rows + gate biases in registers
  float4 wih0[4], wih1[4], wih2[4];
#pragma unroll
  for (int q = 0; q < 4; ++q) {
    wih0[q] = *(const float4*)(Wih + (size_t)(0 * 512 + ru) * Xx + jq * 16 + q * 4);
    wih1[q] = *(const float4*)(Wih + (size_t)(1 * 512 + ru) * Xx + jq * 16 + q * 4);
    wih2[q] = *(const float4*)(Wih + (size_t)(2 * 512 + ru) * Xx + jq * 16 + q * 4);
  }
  const float bs_r = bih[ru] + bhh[ru];
  const float bs_z = bih[512 + ru] + bhh[512 + ru];
  const float bs_i = bih[1024 + ru];
  const float bs_h = bhh[1024 + ru];

  const float* w0p = lds + LDSW_WHH + ((0 * 16 + u) * 8 + jq) * 68;
  const float* w1p = lds + LDSW_WHH + ((1 * 16 + u) * 8 + jq) * 68;
  const float* w2p = lds + LDSW_WHH + ((2 * 16 + u) * 8 + jq) * 68;

  float hprev_own = 0.f;   // h[bA+jq][ru], written by this thread every step

  int nbar = 1;
  gbar(slots, hs, nbar);   // publish init

  for (int k = 1; k < Sx; ++k) {
    const int pp = k & 1, pr = pp ^ 1;
    const int t_in = dir ? (Sx - k) : (k - 1);

    // ---- stage x_in = [x_p, m] into LDS (vectorized, plain loads) ----
    {
      int bl = tid >> 4, sub = tid & 15;
      int b = b0 + bl;
      float* xr = lds + LDSW_XIN + bl * 160 + (sub >> 1) * 20 + (sub & 1) * 8;
      float v[8];
      if (sub < 8) {
        size_t base = ((size_t)b * Sx + t_in) * Fx + sub * 8;
        float4 xa = *(const float4*)(p.x + base);
        float4 xb = *(const float4*)(p.x + base + 4);
        const float* xhp = xhb + ((size_t)dir * Bx + b) * Fx + sub * 8;
        float4 ha  = *(const float4*)(xhp);
        float4 hb4 = *(const float4*)(xhp + 4);
        int mi[8];
        if (u8f) {
          unsigned long long mm = *(const unsigned long long*)(m8 + base);
#pragma unroll
          for (int j = 0; j < 8; ++j) mi[j] = (int)((mm >> (8 * j)) & 0xFF);
        } else {
          int4 ma = *(const int4*)(m32 + base);
          int4 mb = *(const int4*)(m32 + base + 4);
          mi[0] = ma.x; mi[1] = ma.y; mi[2] = ma.z; mi[3] = ma.w;
          mi[4] = mb.x; mi[5] = mb.y; mi[6] = mb.z; mi[7] = mb.w;
        }
        v[0] = mi[0] ? xa.x : ha.x;  v[1] = mi[1] ? xa.y : ha.y;
        v[2] = mi[2] ? xa.z : ha.z;  v[3] = mi[3] ? xa.w : ha.w;
        v[4] = mi[4] ? xb.x : hb4.x; v[5] = mi[5] ? xb.y : hb4.y;
        v[6] = mi[6] ? xb.z : hb4.z; v[7] = mi[7] ? xb.w : hb4.w;
      } else {
        size_t base = ((size_t)b * Sx + t_in) * Fx + (sub - 8) * 8;
        if (u8f) {
          unsigned long long mm = *(const unsigned long long*)(m8 + base);
#pragma unroll
          for (int j = 0; j < 8; ++j) v[j] = (float)((mm >> (8 * j)) & 0xFF);
        } else {
          int4 ma = *(const int4*)(m32 + base);
          int4 mb = *(const int4*)(m32 + base + 4);
          v[0] = (float)ma.x; v[1] = (float)ma.y; v[2] = (float)ma.z; v[3] = (float)ma.w;
          v[4] = (float)mb.x; v[5] = (float)mb.y; v[6] = (float)mb.z; v[7] = (float)mb.w;
        }
      }
      *(float4*)(xr)     = make_float4(v[0], v[1], v[2], v[3]);
      *(float4*)(xr + 4) = make_float4(v[4], v[5], v[6], v[7]);
    }
    __syncthreads();

    float acc0[8], acc1[8], acc2[8], acc3[8];
#pragma unroll
    for (int i = 0; i < 8; ++i) { acc0[i] = 0.f; acc1[i] = 0.f; acc2[i] = 0.f; acc3[i] = 0.f; }

    // ---- gh: Whh slice (LDS) x h_prev (plain cached loads, fresh via acquire) ----
    {
      const float* hrd = hbuf + (size_t)(dir * 2 + pr) * Bx * Hx;
#pragma unroll 2
      for (int jj = 0; jj < 64; jj += 4) {
        float4 w0 = *(const float4*)(w0p + jj);
        float4 w1 = *(const float4*)(w1p + jj);
        float4 w2 = *(const float4*)(w2p + jj);
#pragma unroll
        for (int bb = 0; bb < 8; ++bb) {
          float4 h4 = *(const float4*)(hrd + (size_t)(bA + bb) * Hx + j0 + jj);
          fma4(acc0[bb], w0, h4);
          fma4(acc1[bb], w1, h4);
          fma4(acc3[bb], w2, h4);
        }
      }
    }
    // ---- gi: Wih rows (registers) x x_in (LDS) ----
    {
      const float* xinb = lds + LDSW_XIN;
#pragma unroll
      for (int q = 0; q < 4; ++q) {
        float4 w0 = wih0[q], w1 = wih1[q], w2 = wih2[q];
        int off = jq * 20 + q * 4;
#pragma unroll
        for (int bb = 0; bb < 8; ++bb) {
          float4 xv = *(const float4*)(xinb + (bsub * 8 + bb) * 160 + off);
          fma4(acc0[bb], w0, xv);
          fma4(acc1[bb], w1, xv);
          fma4(acc2[bb], w2, xv);
        }
      }
    }
    // ---- reduce across jq ----
#pragma unroll
    for (int m = 1; m <= 4; m <<= 1) {
#pragma unroll
      for (int bb = 0; bb < 8; ++bb) {
        acc0[bb] += __shfl_xor(acc0[bb], m);
        acc1[bb] += __shfl_xor(acc1[bb], m);
        acc2[bb] += __shfl_xor(acc2[bb], m);
        acc3[bb] += __shfl_xor(acc3[bb], m);
      }
    }
    // ---- gates: lane jq handles batch bA+jq; h_prev from register ----
    {
      int b = bA + jq;
      float sr  = sel8(acc0, jq);
      float sz  = sel8(acc1, jq);
      float sgi = sel8(acc2, jq);
      float sgh = sel8(acc3, jq);
      float r = 1.f / (1.f + __expf(-(sr + bs_r)));
      float z = 1.f / (1.f + __expf(-(sz + bs_z)));
      float n = tanhf(sgi + bs_i + r * (sgh + bs_h));
      float hn = (1.f - z) * n + z * hprev_own;
      hprev_own = hn;
      st_sys(&hbuf[(size_t)(dir * 2 + pp) * Bx * Hx + (size_t)b * Hx + ru], hn);
    }
    ++nbar;
    gbar(slots, hs, nbar);   // h_new visible to group

    // ---- phase B: xhat = Wro@h + bro ; Wout-half partial ----
    {
      const float* hnw  = hbuf + (size_t)(dir * 2 + pp) * Bx * Hx;
      const float* wroL = lds + LDSW_WRO  + fB * 544 + jq * 68;
      const float* wouL = lds + LDSW_WOUT + fB * 544 + jq * 68;
      const float* hb   = hnw + (size_t)bB * Hx + jq * 64;
      float ax = 0.f, ap = 0.f;
#pragma unroll 2
      for (int jj = 0; jj < 64; jj += 4) {
        float4 h4 = *(const float4*)(hb + jj);
        float4 wx = *(const float4*)(wroL + jj);
        float4 wp = *(const float4*)(wouL + jj);
        fma4(ax, wx, h4);
        fma4(ap, wp, h4);
      }
#pragma unroll
      for (int m = 1; m <= 4; m <<= 1) {
        ax += __shfl_xor(ax, m);
        ap += __shfl_xor(ap, m);
      }
      const int T = dir ? (Sx - 1 - k) : k;
      const int f = f0 + fB;
      if (jq == 0) {
        float v = ax + bro[f];
        st_sys(&xhb[((size_t)dir * Bx + bB) * Fx + f], v);
        st_sys(&out_xh[((size_t)bB * Sx + T) * Fx + f], v);
      } else if (jq == 1) {
        st_sys(&pout[((size_t)bB * Sx + T) * Fx + f], ap);   // pure write
      }
    }
    ++nbar;
    gbar(slots, hs, nbar);   // xhb visible for next staging
  }
}

extern "C" void kernel_launch(void* const* d_in, const int* in_sizes, int n_in,
                              void* d_out, int out_size, void* d_ws, size_t ws_size,
                              hipStream_t stream) {
  (void)in_sizes; (void)n_in; (void)out_size; (void)ws_size;
  float* ws = (float*)d_ws;

  detect_kernel<<<1, 512, 0, stream>>>((const unsigned int*)d_in[1], ws);

  BParams p;
  p.x     = (const float*)d_in[0];  p.mask = d_in[1];
  p.Wih_f = (const float*)d_in[2];  p.Whh_f = (const float*)d_in[3];
  p.bih_f = (const float*)d_in[4];  p.bhh_f = (const float*)d_in[5];
  p.Wro_f = (const float*)d_in[6];  p.bro_f = (const float*)d_in[7];
  p.Wih_b = (const float*)d_in[8];  p.Whh_b = (const float*)d_in[9];
  p.bih_b = (const float*)d_in[10]; p.bhh_b = (const float*)d_in[11];
  p.Wro_b = (const float*)d_in[12]; p.bro_b = (const float*)d_in[13];
  p.Wout  = (const float*)d_in[14]; p.bout  = (const float*)d_in[15];
  p.out   = (float*)d_out;
  p.ws    = ws;

  hipFuncSetAttribute(reinterpret_cast<const void*>(birnn_main),
                      hipFuncAttributeMaxDynamicSharedMemorySize,
                      (int)(LDSW_TOTAL * sizeof(float)));
  void* args[] = { (void*)&p };
  hipLaunchCooperativeKernel(reinterpret_cast<void*>(birnn_main),
                             dim3(256), dim3(512), args,
                             (unsigned)(LDSW_TOTAL * sizeof(float)), stream);

  combine_kernel<<<dim3(Bx * Sx * Fx / 256), dim3(256), 0, stream>>>(
      (float*)d_out, ws + PARTB_OFF, (const float*)d_in[15]);
}

// Round 10
// 22060.687 us; speedup vs baseline: 1.2050x; 1.1116x over previous
//
#include <hip/hip_runtime.h>

#define Bx 128
#define Sx 512
#define Fx 64
#define Hx 512
#define Xx 128   // 2F

// ---- workspace float offsets ----
#define PARTB_OFF 0ull                             // bwd Wout-partial [B][S][F]
#define H_OFF     ((size_t)Bx * Sx * Fx)           // 4,194,304
#define XH_OFF    (H_OFF + (size_t)2 * 2 * Bx * Hx)
#define BAR_OFF   (XH_OFF + (size_t)2 * Bx * Fx)   // 4096 ints: 8 grp x 32 slot x 16
#define FLAG_OFF  (BAR_OFF + 4096)

// ---- LDS word offsets ----
#define LDSW_WHH   0
#define LDSW_XIN   26112                       // 3*16*8*68
#define LDSW_WRO   (LDSW_XIN + 32 * 160)
#define LDSW_WOUT  (LDSW_WRO + 2 * 544)
#define LDSW_TOTAL (LDSW_WOUT + 2 * 544 + 16)  // 33424 floats -> 1 wg/CU

struct BParams {
  const float* x; const void* mask;
  const float* Wih_f; const float* Whh_f; const float* bih_f; const float* bhh_f;
  const float* Wro_f; const float* bro_f;
  const float* Wih_b; const float* Whh_b; const float* bih_b; const float* bhh_b;
  const float* Wro_b; const float* bro_b;
  const float* Wout; const float* bout;
  float* out; float* ws;
};

__global__ void detect_kernel(const unsigned int* mask, float* ws) {
  int* bars = (int*)(ws + BAR_OFF);
  int* flag = (int*)(ws + FLAG_OFF);
  int t = threadIdx.x;
  for (int i = t; i < 4096; i += blockDim.x) bars[i] = 0;
  if (t == 0) *flag = 0;
  __syncthreads();
  unsigned int v = 0;
  for (int i = t; i < 4096; i += blockDim.x) v |= mask[i] & 0xFFFFFF00u;
  if (v) atomicOr(flag, 1);
}

__global__ void combine_kernel(float* out, const float* partb, const float* bout) {
  int i = blockIdx.x * blockDim.x + threadIdx.x;
  out[i] = out[i] + partb[i] + bout[i & 63];
}

__device__ __forceinline__ float sel8(const float* a, int idx) {
  float v = a[0];
#pragma unroll
  for (int i = 1; i < 8; ++i) v = (idx == i) ? a[i] : v;
  return v;
}

// System-scope relaxed store: write-through past L2 (never dirty; at the
// coherence point once vmcnt-acked). Proven rounds 7-9.
__device__ __forceinline__ void st_sys(float* p, float v) {
  __hip_atomic_store(p, v, __ATOMIC_RELAXED, __HIP_MEMORY_SCOPE_SYSTEM);
}
__device__ __forceinline__ void st_sys_i(int* p, int v) {
  __hip_atomic_store(p, v, __ATOMIC_RELAXED, __HIP_MEMORY_SCOPE_SYSTEM);
}

// 32-member group barrier, ordinal nbar. Signal path proven in R9 (parallel
// slot stores + agent-relaxed poll). Acquire changed: __threadfence's
// buffer_wbl2+buffer_inv pair -> buffer_inv ONLY. The wbl2 is a full L2 tag
// walk executed every barrier since round 2 (prime suspect for the invariant
// ~20us/barrier); it is semantically vacuous here because every global store
// in this kernel is write-through (L2 never dirty). buffer_inv alone
// invalidates stale L1/L2 copies so plain cached reads refill fresh.
__device__ __forceinline__ void gbar(int* slots, int hs, int nbar) {
  __syncthreads();   // vmcnt(0): all waves' st_sys data at coherence point
  if (threadIdx.x < 64) {
    if (threadIdx.x == 0) st_sys_i(slots + hs * 16, nbar);
    const int* myslot = slots + (threadIdx.x & 31) * 16;
    for (;;) {
      int v = __hip_atomic_load(myslot, __ATOMIC_RELAXED, __HIP_MEMORY_SCOPE_AGENT);
      if (__all(v >= nbar)) break;
      __builtin_amdgcn_s_sleep(1);
    }
    asm volatile("buffer_inv\n\ts_waitcnt vmcnt(0)" ::: "memory");
  }
  __syncthreads();
}

// one j-step of the gh loop: h row [j][bA..bA+8], scalar weights (component C)
#define GH_STEP(C, JOFF) {                                                   \
  const float* hr = hrd + (size_t)(j0 + jj + (JOFF)) * Bx + bA;              \
  float4 ha  = *(const float4*)(hr);                                         \
  float4 hbv = *(const float4*)(hr + 4);                                     \
  float s0 = w0.C, s1 = w1.C, s2 = w2.C;                                     \
  acc0[0]=fmaf(s0,ha.x,acc0[0]);  acc0[1]=fmaf(s0,ha.y,acc0[1]);             \
  acc0[2]=fmaf(s0,ha.z,acc0[2]);  acc0[3]=fmaf(s0,ha.w,acc0[3]);             \
  acc0[4]=fmaf(s0,hbv.x,acc0[4]); acc0[5]=fmaf(s0,hbv.y,acc0[5]);            \
  acc0[6]=fmaf(s0,hbv.z,acc0[6]); acc0[7]=fmaf(s0,hbv.w,acc0[7]);            \
  acc1[0]=fmaf(s1,ha.x,acc1[0]);  acc1[1]=fmaf(s1,ha.y,acc1[1]);             \
  acc1[2]=fmaf(s1,ha.z,acc1[2]);  acc1[3]=fmaf(s1,ha.w,acc1[3]);             \
  acc1[4]=fmaf(s1,hbv.x,acc1[4]); acc1[5]=fmaf(s1,hbv.y,acc1[5]);            \
  acc1[6]=fmaf(s1,hbv.z,acc1[6]); acc1[7]=fmaf(s1,hbv.w,acc1[7]);            \
  acc3[0]=fmaf(s2,ha.x,acc3[0]);  acc3[1]=fmaf(s2,ha.y,acc3[1]);             \
  acc3[2]=fmaf(s2,ha.z,acc3[2]);  acc3[3]=fmaf(s2,ha.w,acc3[3]);             \
  acc3[4]=fmaf(s2,hbv.x,acc3[4]); acc3[5]=fmaf(s2,hbv.y,acc3[5]);            \
  acc3[6]=fmaf(s2,hbv.z,acc3[6]); acc3[7]=fmaf(s2,hbv.w,acc3[7]); }

__global__ void __launch_bounds__(512, 2)
birnn_main(BParams p) {
  extern __shared__ float lds[];

  const int w   = blockIdx.x;
  const int g   = w & 7;         // group = (dir, batch-group)
  const int dir = g >> 2;
  const int bg  = g & 3;
  const int hs  = w >> 3;        // hidden slice 0..31 (= slot index)
  const int b0  = bg * 32;
  const int u0  = hs * 16;
  const int f0  = hs * 2;
  const int tid = threadIdx.x;

  const float* Wih = dir ? p.Wih_b : p.Wih_f;
  const float* Whh = dir ? p.Whh_b : p.Whh_f;
  const float* bih = dir ? p.bih_b : p.bih_f;
  const float* bhh = dir ? p.bhh_b : p.bhh_f;
  const float* Wro = dir ? p.Wro_b : p.Wro_f;
  const float* bro = dir ? p.bro_b : p.bro_f;

  // hbuf layout CHANGED: [dir*2+ping][u(512)][b(128)] -> h_new stores are
  // 8-lane x 4B contiguous (32B chunks) instead of 4B @ 2KB stride.
  float* hbuf  = p.ws + H_OFF;
  // xhb layout CHANGED: [dir][f(64)][b(128)] -> phase-B stores contiguous.
  float* xhb   = p.ws + XH_OFF;
  int*   slots = (int*)(p.ws + BAR_OFF) + g * 512;
  const int u8f = *(const int*)(p.ws + FLAG_OFF);
  const unsigned char* m8  = (const unsigned char*)p.mask;
  const int*           m32 = (const int*)p.mask;

  float* pout   = dir ? (p.ws + PARTB_OFF) : p.out;  // Wout half-partials
  float* out_xh = p.out + (size_t)(1 + dir) * Bx * Sx * Fx;

  // ---- preload LDS-resident weight slices (unchanged layout) ----
  for (int idx = tid; idx < 3 * 16 * 512; idx += 512) {
    int g3 = idx >> 13; int rem = idx & 8191;
    int u = rem >> 9;   int j = rem & 511;
    lds[LDSW_WHH + ((g3 * 16 + u) * 8 + (j >> 6)) * 68 + (j & 63)] =
        Whh[(size_t)(g3 * 512 + u0 + u) * Hx + j];
  }
  for (int idx = tid; idx < 2 * 512; idx += 512) {
    int f = idx >> 9, j = idx & 511;
    lds[LDSW_WRO  + f * 544 + (j >> 6) * 68 + (j & 63)] = Wro[(size_t)(f0 + f) * Hx + j];
    lds[LDSW_WOUT + f * 544 + (j >> 6) * 68 + (j & 63)] =
        p.Wout[(size_t)(f0 + f) * (2 * Hx) + dir * Hx + j];
  }

  // ---- init: h=0 ([u][b], coalesced), xhat=bro, boundary outputs ----
  if (hs == 0) {
    for (int idx = tid; idx < 32 * 512; idx += 512) {
      int u = idx >> 5, bo = idx & 31;
      st_sys(&hbuf[((size_t)(dir * 2 + 0) * Hx + u) * Bx + b0 + bo], 0.f);
    }
  }
  if (tid < 64) {
    int b = b0 + (tid >> 1), f = f0 + (tid & 1);
    float br = bro[f];
    st_sys(&xhb[((size_t)dir * Fx + f) * Bx + b], br);
    int T0 = dir ? (Sx - 1) : 0;
    st_sys(&out_xh[((size_t)b * Sx + T0) * Fx + f], br);
    st_sys(&pout  [((size_t)b * Sx + T0) * Fx + f], 0.f);
  }

  // phase-A map: lane = jq(3b) x ulo(3b); wave = bsub(2b) x uhi(1b)
  const int jq   = tid & 7;
  const int ulo  = (tid >> 3) & 7;
  const int wv   = tid >> 6;
  const int bsub = wv & 3;
  const int uhi  = wv >> 2;
  const int u    = uhi * 8 + ulo;
  const int bA   = b0 + bsub * 8;
  const int ru   = u0 + u;
  const int j0   = jq * 64;
  // phase-B map: lane = jq(3b) x blo(3b); wave = bhi(2b) x fB(1b)
  const int blo  = (tid >> 3) & 7;
  const int bB   = b0 + (wv & 3) * 8 + blo;
  const int fB   = wv >> 2;

  // per-thread-invariant Wih rows + gate biases in registers
  float4 wih0[4], wih1[4], wih2[4];
#pragma unroll
  for (int q = 0; q < 4; ++q) {
    wih0[q] = *(const float4*)(Wih + (size_t)(0 * 512 + ru) * Xx + jq * 16 + q * 4);
    wih1[q] = *(const float4*)(Wih + (size_t)(1 * 512 + ru) * Xx + jq * 16 + q * 4);
    wih2[q] = *(const float4*)(Wih + (size_t)(2 * 512 + ru) * Xx + jq * 16 + q * 4);
  }
  const float bs_r = bih[ru] + bhh[ru];
  const float bs_z = bih[512 + ru] + bhh[512 + ru];
  const float bs_i = bih[1024 + ru];
  const float bs_h = bhh[1024 + ru];

  const float* w0p = lds + LDSW_WHH + ((0 * 16 + u) * 8 + jq) * 68;
  const float* w1p = lds + LDSW_WHH + ((1 * 16 + u) * 8 + jq) * 68;
  const float* w2p = lds + LDSW_WHH + ((2 * 16 + u) * 8 + jq) * 68;

  float hprev_own = 0.f;   // h[bA+jq][ru], written by this thread every step

  int nbar = 1;
  gbar(slots, hs, nbar);   // publish init

  for (int k = 1; k < Sx; ++k) {
    const int pp = k & 1, pr = pp ^ 1;
    const int t_in = dir ? (Sx - k) : (k - 1);

    // ---- stage x_in = [x_p, m] into LDS ----
    {
      int bl = tid >> 4, sub = tid & 15;
      int b = b0 + bl;
      float* xr = lds + LDSW_XIN + bl * 160 + (sub >> 1) * 20 + (sub & 1) * 8;
      float v[8];
      if (sub < 8) {
        size_t base = ((size_t)b * Sx + t_in) * Fx + sub * 8;
        float4 xa = *(const float4*)(p.x + base);
        float4 xb = *(const float4*)(p.x + base + 4);
        const float* xhp = xhb + ((size_t)dir * Fx + sub * 8) * Bx + b;
        float h0 = xhp[0 * Bx], h1 = xhp[1 * Bx], h2 = xhp[2 * Bx], h3 = xhp[3 * Bx];
        float h4 = xhp[4 * Bx], h5 = xhp[5 * Bx], h6 = xhp[6 * Bx], h7 = xhp[7 * Bx];
        int mi[8];
        if (u8f) {
          unsigned long long mm = *(const unsigned long long*)(m8 + base);
#pragma unroll
          for (int j = 0; j < 8; ++j) mi[j] = (int)((mm >> (8 * j)) & 0xFF);
        } else {
          int4 ma = *(const int4*)(m32 + base);
          int4 mb = *(const int4*)(m32 + base + 4);
          mi[0] = ma.x; mi[1] = ma.y; mi[2] = ma.z; mi[3] = ma.w;
          mi[4] = mb.x; mi[5] = mb.y; mi[6] = mb.z; mi[7] = mb.w;
        }
        v[0] = mi[0] ? xa.x : h0;  v[1] = mi[1] ? xa.y : h1;
        v[2] = mi[2] ? xa.z : h2;  v[3] = mi[3] ? xa.w : h3;
        v[4] = mi[4] ? xb.x : h4;  v[5] = mi[5] ? xb.y : h5;
        v[6] = mi[6] ? xb.z : h6;  v[7] = mi[7] ? xb.w : h7;
      } else {
        size_t base = ((size_t)b * Sx + t_in) * Fx + (sub - 8) * 8;
        if (u8f) {
          unsigned long long mm = *(const unsigned long long*)(m8 + base);
#pragma unroll
          for (int j = 0; j < 8; ++j) v[j] = (float)((mm >> (8 * j)) & 0xFF);
        } else {
          int4 ma = *(const int4*)(m32 + base);
          int4 mb = *(const int4*)(m32 + base + 4);
          v[0] = (float)ma.x; v[1] = (float)ma.y; v[2] = (float)ma.z; v[3] = (float)ma.w;
          v[4] = (float)mb.x; v[5] = (float)mb.y; v[6] = (float)mb.z; v[7] = (float)mb.w;
        }
      }
      *(float4*)(xr)     = make_float4(v[0], v[1], v[2], v[3]);
      *(float4*)(xr + 4) = make_float4(v[4], v[5], v[6], v[7]);
    }
    __syncthreads();

    float acc0[8], acc1[8], acc2[8], acc3[8];
#pragma unroll
    for (int i = 0; i < 8; ++i) { acc0[i] = 0.f; acc1[i] = 0.f; acc2[i] = 0.f; acc3[i] = 0.f; }

    // ---- gh: Whh slice (LDS) x h_prev ([u][b] layout; j ascending ->
    //      identical accumulation order to rounds 2-9) ----
    {
      const float* hrd = hbuf + (size_t)(dir * 2 + pr) * Hx * Bx;
#pragma unroll 2
      for (int jj = 0; jj < 64; jj += 4) {
        float4 w0 = *(const float4*)(w0p + jj);
        float4 w1 = *(const float4*)(w1p + jj);
        float4 w2 = *(const float4*)(w2p + jj);
        GH_STEP(x, 0)
        GH_STEP(y, 1)
        GH_STEP(z, 2)
        GH_STEP(w, 3)
      }
    }
    // ---- gi: Wih rows (registers) x x_in (LDS) ----
    {
      const float* xinb = lds + LDSW_XIN;
#pragma unroll
      for (int q = 0; q < 4; ++q) {
        float4 w0 = wih0[q], w1 = wih1[q], w2 = wih2[q];
        int off = jq * 20 + q * 4;
#pragma unroll
        for (int bb = 0; bb < 8; ++bb) {
          float4 xv = *(const float4*)(xinb + (bsub * 8 + bb) * 160 + off);
          acc0[bb] = fmaf(w0.x, xv.x, acc0[bb]); acc0[bb] = fmaf(w0.y, xv.y, acc0[bb]);
          acc0[bb] = fmaf(w0.z, xv.z, acc0[bb]); acc0[bb] = fmaf(w0.w, xv.w, acc0[bb]);
          acc1[bb] = fmaf(w1.x, xv.x, acc1[bb]); acc1[bb] = fmaf(w1.y, xv.y, acc1[bb]);
          acc1[bb] = fmaf(w1.z, xv.z, acc1[bb]); acc1[bb] = fmaf(w1.w, xv.w, acc1[bb]);
          acc2[bb] = fmaf(w2.x, xv.x, acc2[bb]); acc2[bb] = fmaf(w2.y, xv.y, acc2[bb]);
          acc2[bb] = fmaf(w2.z, xv.z, acc2[bb]); acc2[bb] = fmaf(w2.w, xv.w, acc2[bb]);
        }
      }
    }
    // ---- reduce across jq ----
#pragma unroll
    for (int m = 1; m <= 4; m <<= 1) {
#pragma unroll
      for (int bb = 0; bb < 8; ++bb) {
        acc0[bb] += __shfl_xor(acc0[bb], m);
        acc1[bb] += __shfl_xor(acc1[bb], m);
        acc2[bb] += __shfl_xor(acc2[bb], m);
        acc3[bb] += __shfl_xor(acc3[bb], m);
      }
    }
    // ---- gates: lane jq handles batch bA+jq; h_prev from register ----
    {
      int b = bA + jq;
      float sr  = sel8(acc0, jq);
      float sz  = sel8(acc1, jq);
      float sgi = sel8(acc2, jq);
      float sgh = sel8(acc3, jq);
      float r = 1.f / (1.f + __expf(-(sr + bs_r)));
      float z = 1.f / (1.f + __expf(-(sz + bs_z)));
      float n = tanhf(sgi + bs_i + r * (sgh + bs_h));
      float hn = (1.f - z) * n + z * hprev_own;
      hprev_own = hn;
      // [u][b]: lanes jq=0..7 write consecutive b -> 32B coalesced chunk
      st_sys(&hbuf[((size_t)(dir * 2 + pp) * Hx + ru) * Bx + b], hn);
    }
    ++nbar;
    gbar(slots, hs, nbar);   // h_new visible to group

    // ---- phase B: xhat = Wro@h + bro ; Wout-half partial ----
    {
      const float* hnw  = hbuf + (size_t)(dir * 2 + pp) * Hx * Bx;
      const float* wroL = lds + LDSW_WRO  + fB * 544 + jq * 68;
      const float* wouL = lds + LDSW_WOUT + fB * 544 + jq * 68;
      const float* hcol = hnw + (size_t)j0 * Bx + bB;   // h[j][bB], stride Bx
      float ax = 0.f, ap = 0.f;
#pragma unroll 4
      for (int jj = 0; jj < 64; jj += 4) {
        float4 wx = *(const float4*)(wroL + jj);
        float4 wp = *(const float4*)(wouL + jj);
        float h0 = hcol[(size_t)(jj + 0) * Bx];
        float h1 = hcol[(size_t)(jj + 1) * Bx];
        float h2 = hcol[(size_t)(jj + 2) * Bx];
        float h3 = hcol[(size_t)(jj + 3) * Bx];
        ax = fmaf(wx.x, h0, ax); ap = fmaf(wp.x, h0, ap);
        ax = fmaf(wx.y, h1, ax); ap = fmaf(wp.y, h1, ap);
        ax = fmaf(wx.z, h2, ax); ap = fmaf(wp.z, h2, ap);
        ax = fmaf(wx.w, h3, ax); ap = fmaf(wp.w, h3, ap);
      }
#pragma unroll
      for (int m = 1; m <= 4; m <<= 1) {
        ax += __shfl_xor(ax, m);
        ap += __shfl_xor(ap, m);
      }
      const int T = dir ? (Sx - 1 - k) : k;
      const int f = f0 + fB;
      if (jq == 0) {
        float v = ax + bro[f];
        st_sys(&xhb[((size_t)dir * Fx + f) * Bx + bB], v);   // [f][b] coalesced
        st_sys(&out_xh[((size_t)bB * Sx + T) * Fx + f], v);
      } else if (jq == 1) {
        st_sys(&pout[((size_t)bB * Sx + T) * Fx + f], ap);   // pure write
      }
    }
    ++nbar;
    gbar(slots, hs, nbar);   // xhb visible for next staging
  }
}

extern "C" void kernel_launch(void* const* d_in, const int* in_sizes, int n_in,
                              void* d_out, int out_size, void* d_ws, size_t ws_size,
                              hipStream_t stream) {
  (void)in_sizes; (void)n_in; (void)out_size; (void)ws_size;
  float* ws = (float*)d_ws;

  detect_kernel<<<1, 512, 0, stream>>>((const unsigned int*)d_in[1], ws);

  BParams p;
  p.x     = (const float*)d_in[0];  p.mask = d_in[1];
  p.Wih_f = (const float*)d_in[2];  p.Whh_f = (const float*)d_in[3];
  p.bih_f = (const float*)d_in[4];  p.bhh_f = (const float*)d_in[5];
  p.Wro_f = (const float*)d_in[6];  p.bro_f = (const float*)d_in[7];
  p.Wih_b = (const float*)d_in[8];  p.Whh_b = (const float*)d_in[9];
  p.bih_b = (const float*)d_in[10]; p.bhh_b = (const float*)d_in[11];
  p.Wro_b = (const float*)d_in[12]; p.bro_b = (const float*)d_in[13];
  p.Wout  = (const float*)d_in[14]; p.bout  = (const float*)d_in[15];
  p.out   = (float*)d_out;
  p.ws    = ws;

  hipFuncSetAttribute(reinterpret_cast<const void*>(birnn_main),
                      hipFuncAttributeMaxDynamicSharedMemorySize,
                      (int)(LDSW_TOTAL * sizeof(float)));
  void* args[] = { (void*)&p };
  hipLaunchCooperativeKernel(reinterpret_cast<void*>(birnn_main),
                             dim3(256), dim3(512), args,
                             (unsigned)(LDSW_TOTAL * sizeof(float)), stream);

  combine_kernel<<<dim3(Bx * Sx * Fx / 256), dim3(256), 0, stream>>>(
      (float*)d_out, ws + PARTB_OFF, (const float*)d_in[15]);
}